// Round 7
// baseline (292.119 us; speedup 1.0000x reference)
//
#include <hip/hip_runtime.h>
#include <hip/hip_bf16.h>

typedef __attribute__((ext_vector_type(8))) short short8;
typedef __attribute__((ext_vector_type(4))) short short4v;
typedef __attribute__((ext_vector_type(4))) float floatx4;
typedef unsigned short u16;

#define B_SZ 4
#define NH   16
#define SEQ  2048
#define DM   1024
#define DK   64
#define M_ROWS (B_SZ * SEQ)   // 8192

__device__ __forceinline__ u16 f2bf(float f) {
  unsigned u = __float_as_uint(f);
  u += 0x7fff + ((u >> 16) & 1);   // RNE
  return (u16)(u >> 16);
}

// async global->LDS: dest = wave-uniform base + lane*16B (verified constraint)
__device__ __forceinline__ void async_copy16(const u16* g, const short* lds) {
  __builtin_amdgcn_global_load_lds(
      (const __attribute__((address_space(1))) void*)g,
      (__attribute__((address_space(3))) void*)lds,
      16, 0, 0);
}

// ---------------------------------------------------------------------------
// cvt4: fp32->bf16 for x (y=0) and Wq/Wk/Wv (y=1..3). grid=(1024,4).
// ---------------------------------------------------------------------------
__global__ __launch_bounds__(256)
void cvt4_kernel(const float* __restrict__ x,
                 const float* __restrict__ wq, const float* __restrict__ wk,
                 const float* __restrict__ wv,
                 u16* __restrict__ xb, u16* __restrict__ wb)
{
  const int y = blockIdx.y;
  const float* src; u16* dst; int n4;
  if (y == 0)      { src = x;  dst = xb;                 n4 = (M_ROWS * DM) / 4; }
  else if (y == 1) { src = wq; dst = wb;                 n4 = (DM * DM) / 4; }
  else if (y == 2) { src = wk; dst = wb + DM * DM;       n4 = (DM * DM) / 4; }
  else             { src = wv; dst = wb + 2 * DM * DM;   n4 = (DM * DM) / 4; }
  for (int i = blockIdx.x * 256 + threadIdx.x; i < n4; i += gridDim.x * 256) {
    floatx4 v = ((const floatx4*)src)[i];
    short4v s;
#pragma unroll
    for (int e = 0; e < 4; ++e) s[e] = (short)f2bf(v[e]);
    ((short4v*)dst)[i] = s;
  }
}

__global__ __launch_bounds__(256)
void cvt1_kernel(const float* __restrict__ in, u16* __restrict__ out, int n4)
{
  for (int i = blockIdx.x * 256 + threadIdx.x; i < n4; i += gridDim.x * 256) {
    floatx4 v = ((const floatx4*)in)[i];
    short4v s;
#pragma unroll
    for (int e = 0; e < 4; ++e) s[e] = (short)f2bf(v[e]);
    ((short4v*)out)[i] = s;
  }
}

// ---------------------------------------------------------------------------
// 128x128 GEMM core, both sides bf16 + global_load_lds (m97 structure):
// C = A(MxK bf16 row-major) * Wb^T (Wb NxK bf16 row-major).
// ---------------------------------------------------------------------------
__device__ __forceinline__ void gemm_core_bb(
    const u16* __restrict__ A, const u16* __restrict__ Wb,
    int m0, int n0, floatx4 acc[4][4])
{
  __shared__ short As[128 * 32];
  __shared__ short Bs[128 * 32];

  const int tid  = threadIdx.x;
  const int w    = tid >> 6;
  const int lane = tid & 63;
  const int wm   = w >> 1, wn = w & 1;
  const int quad = lane >> 4, l16 = lane & 15;
  const int r4   = lane >> 2, c4 = lane & 3;

#pragma unroll
  for (int i = 0; i < 4; ++i)
#pragma unroll
    for (int j = 0; j < 4; ++j)
      acc[i][j] = floatx4{0.f, 0.f, 0.f, 0.f};

  for (int kt = 0; kt < (DM >> 5); ++kt) {
    const int kk = kt * 32;
    __syncthreads();
#pragma unroll
    for (int c = 0; c < 2; ++c) {
      const int rowA = w * 32 + c * 16;   // wave-uniform
      async_copy16(A  + (size_t)(m0 + rowA + r4) * DM + kk + c4 * 8, As + rowA * 32);
      async_copy16(Wb + (size_t)(n0 + rowA + r4) * DM + kk + c4 * 8, Bs + rowA * 32);
    }
    __syncthreads();

    short8 afr[4], bfr[4];
#pragma unroll
    for (int t = 0; t < 4; ++t) {
      afr[t] = *(const short8*)(As + (wm * 64 + t * 16 + l16) * 32 + quad * 8);
      bfr[t] = *(const short8*)(Bs + (wn * 64 + t * 16 + l16) * 32 + quad * 8);
    }
#pragma unroll
    for (int i = 0; i < 4; ++i)
#pragma unroll
      for (int j = 0; j < 4; ++j)
        acc[i][j] = __builtin_amdgcn_mfma_f32_16x16x32_bf16(afr[i], bfr[j], acc[i][j], 0, 0, 0);
  }
}

// ---------------------------------------------------------------------------
// Fused QKV projection. grid = (64, 24): y/8 selects Q/K/V, y%8 = n-block.
// Weights pre-converted bf16, packed [3][DM][DM].
// __launch_bounds__(256,4): occupancy probe — 124 unified regs fits 4 waves/EU.
// ---------------------------------------------------------------------------
__global__ __launch_bounds__(256, 4)
void qkv_kernel(const u16* __restrict__ xb, const u16* __restrict__ wb,
                const float* __restrict__ bq, const float* __restrict__ bk,
                const float* __restrict__ bv,
                u16* __restrict__ Qo, u16* __restrict__ Ko, u16* __restrict__ Vto)
{
  const int mat = blockIdx.y >> 3;
  const int m0  = blockIdx.x * 128;
  const int n0  = (blockIdx.y & 7) * 128;
  const u16* W      = wb + (size_t)mat * DM * DM;
  const float* bias = (mat == 0) ? bq : (mat == 1) ? bk : bv;
  u16* dst          = (mat == 0) ? Qo : (mat == 1) ? Ko : Vto;

  floatx4 acc[4][4];
  gemm_core_bb(xb, W, m0, n0, acc);

  const int tid = threadIdx.x;
  const int w = tid >> 6, lane = tid & 63;
  const int wm = w >> 1, wn = w & 1, quad = lane >> 4, l16 = lane & 15;

#pragma unroll
  for (int nt = 0; nt < 4; ++nt) {
    const int n = n0 + wn * 64 + nt * 16 + l16;
    const float bb = bias[n];
    const int h = n >> 6, d = n & 63;
#pragma unroll
    for (int mt = 0; mt < 4; ++mt)
#pragma unroll
      for (int r = 0; r < 4; ++r) {
        const int m = m0 + wm * 64 + mt * 16 + quad * 4 + r;
        const int b = m >> 11, s = m & 2047;
        const float v = acc[mt][nt][r] + bb;
        size_t off;
        if (mat < 2) off = ((size_t)(b * NH + h) * SEQ + s) * DK + d;   // (b,h,s,d)
        else         off = ((size_t)(b * NH + h) * DK + d) * SEQ + s;   // (b,h,d,s)
        dst[off] = f2bf(v);
      }
  }
}

// ---------------------------------------------------------------------------
// Flash attention, causal, exp2-domain, no-rescale online softmax.
// grid = (64 bh, 16 qt-reversed). Block = 128 q-rows, 4 waves x 32 rows.
// __launch_bounds__(256,3): occupancy probe (live state ~110 regs).
// ---------------------------------------------------------------------------
#define AT_STR 72
__global__ __launch_bounds__(256, 3)
void attn_kernel(const u16* __restrict__ Q, const u16* __restrict__ Kx,
                 const u16* __restrict__ Vt, u16* __restrict__ O)
{
  __shared__ short Ks[64 * 64];
  __shared__ short Vs[64 * 64];
  __shared__ short Ps[4 * 32 * AT_STR];

  const int bh  = blockIdx.x;
  const int qtb = 15 - (int)blockIdx.y;
  const int q0  = qtb * 128;
  const int tid = threadIdx.x;
  const int w = tid >> 6, lane = tid & 63;
  const int quad = lane >> 4, l16 = lane & 15;
  const int r8 = lane >> 3, c8 = lane & 7;

  const u16* Qh = Q  + (size_t)bh * SEQ * DK;
  const u16* Kh = Kx + (size_t)bh * SEQ * DK;
  const u16* Vh = Vt + (size_t)bh * DK * SEQ;

  short8 qf[2][2];
#pragma unroll
  for (int qp = 0; qp < 2; ++qp) {
    const int qrow = q0 + w * 32 + qp * 16 + l16;
#pragma unroll
    for (int h = 0; h < 2; ++h)
      qf[qp][h] = *(const short8*)(Qh + (size_t)qrow * DK + h * 32 + quad * 8);
  }

  short8 vone;
#pragma unroll
  for (int j = 0; j < 8; ++j) vone[j] = (l16 == 0) ? (short)0x3F80 : (short)0;

  floatx4 o[2][4], ls[2];
#pragma unroll
  for (int qp = 0; qp < 2; ++qp) {
    ls[qp] = floatx4{0.f, 0.f, 0.f, 0.f};
#pragma unroll
    for (int dt = 0; dt < 4; ++dt) o[qp][dt] = floatx4{0.f, 0.f, 0.f, 0.f};
  }

  const float SC2 = 0.18033688011f;   // (1/8) * log2(e)
  const int ktmax = 2 * qtb + 2;

  for (int kt = 0; kt < ktmax; ++kt) {
    const int k0 = kt * 64;
    __syncthreads();
#pragma unroll
    for (int c = 0; c < 2; ++c) {
      const int row8 = w * 16 + c * 8;   // wave-uniform
      const int sw   = (c8 ^ r8) * 8;
      async_copy16(Kh + (size_t)(k0 + row8 + r8) * DK + sw, Ks + row8 * 64);
      async_copy16(Vh + (size_t)(row8 + r8) * SEQ + k0 + sw, Vs + row8 * 64);
    }
    __syncthreads();

    short8 kf[4][2], vf[4][2];
#pragma unroll
    for (int nt = 0; nt < 4; ++nt)
#pragma unroll
      for (int h = 0; h < 2; ++h) {
        kf[nt][h] = *(const short8*)(Ks + (nt * 16 + l16) * 64 + (((h * 4 + quad) ^ (l16 & 7)) * 8));
        vf[nt][h] = *(const short8*)(Vs + (nt * 16 + l16) * 64 + (((h * 4 + quad) ^ (l16 & 7)) * 8));
      }

#pragma unroll
    for (int qp = 0; qp < 2; ++qp) {
      const int frag0 = q0 + w * 32 + qp * 16;
      if (k0 <= frag0 + 15) {
        floatx4 sc[4];
#pragma unroll
        for (int nt = 0; nt < 4; ++nt) {
          floatx4 z = floatx4{0.f, 0.f, 0.f, 0.f};
          z = __builtin_amdgcn_mfma_f32_16x16x32_bf16(qf[qp][0], kf[nt][0], z, 0, 0, 0);
          z = __builtin_amdgcn_mfma_f32_16x16x32_bf16(qf[qp][1], kf[nt][1], z, 0, 0, 0);
          sc[nt] = z;
        }
        const bool diag = (k0 + 63 > frag0);
#pragma unroll
        for (int nt = 0; nt < 4; ++nt)
#pragma unroll
          for (int r = 0; r < 4; ++r) {
            float s = sc[nt][r] * SC2;
            if (diag) {
              const int col = k0 + nt * 16 + l16;
              const int row = frag0 + quad * 4 + r;
              if (col > row) s = -1e30f;
            }
            sc[nt][r] = __builtin_amdgcn_exp2f(s);
          }
        short* Pp = Ps + (w * 32 + qp * 16) * AT_STR;
#pragma unroll
        for (int nt = 0; nt < 4; ++nt)
#pragma unroll
          for (int r = 0; r < 4; ++r)
            Pp[(quad * 4 + r) * AT_STR + nt * 16 + l16] = (short)f2bf(sc[nt][r]);
        short8 pf[2];
#pragma unroll
        for (int h = 0; h < 2; ++h)
          pf[h] = *(const short8*)(Pp + l16 * AT_STR + h * 32 + quad * 8);
#pragma unroll
        for (int dt = 0; dt < 4; ++dt) {
          o[qp][dt] = __builtin_amdgcn_mfma_f32_16x16x32_bf16(pf[0], vf[dt][0], o[qp][dt], 0, 0, 0);
          o[qp][dt] = __builtin_amdgcn_mfma_f32_16x16x32_bf16(pf[1], vf[dt][1], o[qp][dt], 0, 0, 0);
        }
        ls[qp] = __builtin_amdgcn_mfma_f32_16x16x32_bf16(pf[0], vone, ls[qp], 0, 0, 0);
        ls[qp] = __builtin_amdgcn_mfma_f32_16x16x32_bf16(pf[1], vone, ls[qp], 0, 0, 0);
      }
    }
  }

  const int b = bh >> 4, h = bh & 15;
#pragma unroll
  for (int qp = 0; qp < 2; ++qp) {
    const int frag0 = q0 + w * 32 + qp * 16;
#pragma unroll
    for (int r = 0; r < 4; ++r) {
      const float lv  = __shfl(ls[qp][r], lane & 48);
      const float inv = 1.0f / fmaxf(lv, 1e-20f);
      const int row   = frag0 + quad * 4 + r;
      const size_t base = ((size_t)b * SEQ + row) * DM + h * DK;
#pragma unroll
      for (int dt = 0; dt < 4; ++dt)
        O[base + dt * 16 + l16] = f2bf(o[qp][dt][r] * inv);
    }
  }
}

// ---------------------------------------------------------------------------
// Output projection: out = O'(bf16) @ Wo_b^T + bo, fp32 out. grid = (64, 8).
// ---------------------------------------------------------------------------
__global__ __launch_bounds__(256, 4)
void oproj_kernel(const u16* __restrict__ A, const u16* __restrict__ Wob,
                  const float* __restrict__ bo, float* __restrict__ out)
{
  const int m0 = blockIdx.x * 128, n0 = blockIdx.y * 128;
  floatx4 acc[4][4];
  gemm_core_bb(A, Wob, m0, n0, acc);

  const int tid = threadIdx.x;
  const int w = tid >> 6, lane = tid & 63;
  const int wm = w >> 1, wn = w & 1, quad = lane >> 4, l16 = lane & 15;

#pragma unroll
  for (int nt = 0; nt < 4; ++nt) {
    const int n = n0 + wn * 64 + nt * 16 + l16;
    const float bb = bo[n];
#pragma unroll
    for (int mt = 0; mt < 4; ++mt)
#pragma unroll
      for (int r = 0; r < 4; ++r) {
        const int m = m0 + wm * 64 + mt * 16 + quad * 4 + r;
        out[(size_t)m * DM + n] = acc[mt][nt][r] + bb;
      }
  }
}

extern "C" void kernel_launch(void* const* d_in, const int* in_sizes, int n_in,
                              void* d_out, int out_size, void* d_ws, size_t ws_size,
                              hipStream_t stream)
{
  const float* x  = (const float*)d_in[0];
  const float* Wq = (const float*)d_in[1];
  const float* bq = (const float*)d_in[2];
  const float* Wk = (const float*)d_in[3];
  const float* bk = (const float*)d_in[4];
  const float* Wv = (const float*)d_in[5];
  const float* bv = (const float*)d_in[6];
  const float* Wo = (const float*)d_in[7];
  const float* bo = (const float*)d_in[8];
  float* out = (float*)d_out;

  // ws (64 MiB): Q, K, Vt, O'  (qws doubles as Wo_b after attn)
  u16* qws  = (u16*)d_ws;                       // (b,h,s,d)  bf16, 16 MiB
  u16* kws  = qws  + (size_t)M_ROWS * DM;       // (b,h,s,d)  bf16, 16 MiB
  u16* vtws = kws  + (size_t)M_ROWS * DM;       // (b,h,d,s)  bf16, 16 MiB
  u16* ows  = vtws + (size_t)M_ROWS * DM;       // O' (b,s,h*d) bf16, 16 MiB

  // d_out doubles as scratch until oproj overwrites all of it:
  //   [0, 16 MiB)  : x bf16
  //   [16, 22 MiB) : Wq/Wk/Wv bf16 packed [3][DM][DM]
  u16* xb = (u16*)d_out;
  u16* wb = xb + (size_t)M_ROWS * DM;
  u16* wo_b = qws;                              // qws dead after attn

  cvt4_kernel<<<dim3(1024, 4), 256, 0, stream>>>(x, Wq, Wk, Wv, xb, wb);
  qkv_kernel <<<dim3(64, 24), 256, 0, stream>>>(xb, wb, bq, bk, bv, qws, kws, vtws);
  attn_kernel<<<dim3(64, 16), 256, 0, stream>>>(qws, kws, vtws, ows);
  cvt1_kernel<<<dim3(1024), 256, 0, stream>>>(Wo, wo_b, (DM * DM) / 4);
  oproj_kernel<<<dim3(64, 8), 256, 0, stream>>>(ows, wo_b, bo, out);
}

// Round 8
// 279.089 us; speedup vs baseline: 1.0467x; 1.0467x over previous
//
#include <hip/hip_runtime.h>
#include <hip/hip_bf16.h>

typedef __attribute__((ext_vector_type(8))) short short8;
typedef __attribute__((ext_vector_type(4))) short short4v;
typedef __attribute__((ext_vector_type(4))) float floatx4;
typedef unsigned short u16;

#define B_SZ 4
#define NH   16
#define SEQ  2048
#define DM   1024
#define DK   64
#define M_ROWS (B_SZ * SEQ)   // 8192

__device__ __forceinline__ u16 f2bf(float f) {
  unsigned u = __float_as_uint(f);
  u += 0x7fff + ((u >> 16) & 1);   // RNE
  return (u16)(u >> 16);
}
// round-nearest-away: 2 insts; differs from RNE only on exact ties
__device__ __forceinline__ u16 f2bf_fast(float f) {
  return (u16)((__float_as_uint(f) + 0x8000u) >> 16);
}

// async global->LDS: dest = wave-uniform base + lane*16B (verified constraint)
__device__ __forceinline__ void async_copy16(const u16* g, const short* lds) {
  __builtin_amdgcn_global_load_lds(
      (const __attribute__((address_space(1))) void*)g,
      (__attribute__((address_space(3))) void*)lds,
      16, 0, 0);
}

// ---------------------------------------------------------------------------
// cvt4: fp32->bf16 for x (y=0) and Wq/Wk/Wv (y=1..3). grid=(1024,4).
// ---------------------------------------------------------------------------
__global__ __launch_bounds__(256)
void cvt4_kernel(const float* __restrict__ x,
                 const float* __restrict__ wq, const float* __restrict__ wk,
                 const float* __restrict__ wv,
                 u16* __restrict__ xb, u16* __restrict__ wb)
{
  const int y = blockIdx.y;
  const float* src; u16* dst; int n4;
  if (y == 0)      { src = x;  dst = xb;                 n4 = (M_ROWS * DM) / 4; }
  else if (y == 1) { src = wq; dst = wb;                 n4 = (DM * DM) / 4; }
  else if (y == 2) { src = wk; dst = wb + DM * DM;       n4 = (DM * DM) / 4; }
  else             { src = wv; dst = wb + 2 * DM * DM;   n4 = (DM * DM) / 4; }
  for (int i = blockIdx.x * 256 + threadIdx.x; i < n4; i += gridDim.x * 256) {
    floatx4 v = ((const floatx4*)src)[i];
    short4v s;
#pragma unroll
    for (int e = 0; e < 4; ++e) s[e] = (short)f2bf(v[e]);
    ((short4v*)dst)[i] = s;
  }
}

__global__ __launch_bounds__(256)
void cvt1_kernel(const float* __restrict__ in, u16* __restrict__ out, int n4)
{
  for (int i = blockIdx.x * 256 + threadIdx.x; i < n4; i += gridDim.x * 256) {
    floatx4 v = ((const floatx4*)in)[i];
    short4v s;
#pragma unroll
    for (int e = 0; e < 4; ++e) s[e] = (short)f2bf(v[e]);
    ((short4v*)out)[i] = s;
  }
}

// ---------------------------------------------------------------------------
// 128x128 GEMM core, both sides bf16 + global_load_lds (m97 structure).
// ---------------------------------------------------------------------------
__device__ __forceinline__ void gemm_core_bb(
    const u16* __restrict__ A, const u16* __restrict__ Wb,
    int m0, int n0, floatx4 acc[4][4])
{
  __shared__ short As[128 * 32];
  __shared__ short Bs[128 * 32];

  const int tid  = threadIdx.x;
  const int w    = tid >> 6;
  const int lane = tid & 63;
  const int wm   = w >> 1, wn = w & 1;
  const int quad = lane >> 4, l16 = lane & 15;
  const int r4   = lane >> 2, c4 = lane & 3;

#pragma unroll
  for (int i = 0; i < 4; ++i)
#pragma unroll
    for (int j = 0; j < 4; ++j)
      acc[i][j] = floatx4{0.f, 0.f, 0.f, 0.f};

  for (int kt = 0; kt < (DM >> 5); ++kt) {
    const int kk = kt * 32;
    __syncthreads();
#pragma unroll
    for (int c = 0; c < 2; ++c) {
      const int rowA = w * 32 + c * 16;   // wave-uniform
      async_copy16(A  + (size_t)(m0 + rowA + r4) * DM + kk + c4 * 8, As + rowA * 32);
      async_copy16(Wb + (size_t)(n0 + rowA + r4) * DM + kk + c4 * 8, Bs + rowA * 32);
    }
    __syncthreads();

    short8 afr[4], bfr[4];
#pragma unroll
    for (int t = 0; t < 4; ++t) {
      afr[t] = *(const short8*)(As + (wm * 64 + t * 16 + l16) * 32 + quad * 8);
      bfr[t] = *(const short8*)(Bs + (wn * 64 + t * 16 + l16) * 32 + quad * 8);
    }
#pragma unroll
    for (int i = 0; i < 4; ++i)
#pragma unroll
      for (int j = 0; j < 4; ++j)
        acc[i][j] = __builtin_amdgcn_mfma_f32_16x16x32_bf16(afr[i], bfr[j], acc[i][j], 0, 0, 0);
  }
}

// ---------------------------------------------------------------------------
// Fused QKV projection. grid = (64, 24): y/8 selects Q/K/V, y%8 = n-block.
// Q is pre-scaled by (1/sqrt(dk))*log2(e) so attn can exp2 raw QK sums.
// ---------------------------------------------------------------------------
__global__ __launch_bounds__(256, 2)
void qkv_kernel(const u16* __restrict__ xb, const u16* __restrict__ wb,
                const float* __restrict__ bq, const float* __restrict__ bk,
                const float* __restrict__ bv,
                u16* __restrict__ Qo, u16* __restrict__ Ko, u16* __restrict__ Vto)
{
  const int mat = blockIdx.y >> 3;
  const int m0  = blockIdx.x * 128;
  const int n0  = (blockIdx.y & 7) * 128;
  const u16* W      = wb + (size_t)mat * DM * DM;
  const float* bias = (mat == 0) ? bq : (mat == 1) ? bk : bv;
  u16* dst          = (mat == 0) ? Qo : (mat == 1) ? Ko : Vto;
  const float psc   = (mat == 0) ? 0.18033688011f : 1.0f;   // (1/8)*log2(e)

  floatx4 acc[4][4];
  gemm_core_bb(xb, W, m0, n0, acc);

  const int tid = threadIdx.x;
  const int w = tid >> 6, lane = tid & 63;
  const int wm = w >> 1, wn = w & 1, quad = lane >> 4, l16 = lane & 15;

#pragma unroll
  for (int nt = 0; nt < 4; ++nt) {
    const int n = n0 + wn * 64 + nt * 16 + l16;
    const float bb = bias[n];
    const int h = n >> 6, d = n & 63;
#pragma unroll
    for (int mt = 0; mt < 4; ++mt)
#pragma unroll
      for (int r = 0; r < 4; ++r) {
        const int m = m0 + wm * 64 + mt * 16 + quad * 4 + r;
        const int b = m >> 11, s = m & 2047;
        const float v = (acc[mt][nt][r] + bb) * psc;
        size_t off;
        if (mat < 2) off = ((size_t)(b * NH + h) * SEQ + s) * DK + d;   // (b,h,s,d)
        else         off = ((size_t)(b * NH + h) * DK + d) * SEQ + s;   // (b,h,d,s)
        dst[off] = f2bf(v);
      }
  }
}

// ---------------------------------------------------------------------------
// Flash attention, causal, exp2-domain, no-rescale softmax.
// grid = (64 bh, 8 pairs): each block runs q-tiles (15-y) then (y) -> uniform
// 34 k-iters/block, no straggler tail. 4 waves x 32 q-rows per tile.
// ---------------------------------------------------------------------------
#define AT_STR 72
__global__ __launch_bounds__(256, 2)
void attn_kernel(const u16* __restrict__ Q, const u16* __restrict__ Kx,
                 const u16* __restrict__ Vt, u16* __restrict__ O)
{
  __shared__ short Ks[64 * 64];
  __shared__ short Vs[64 * 64];
  __shared__ short Ps[4 * 32 * AT_STR];

  const int bh  = blockIdx.x;
  const int tid = threadIdx.x;
  const int w = tid >> 6, lane = tid & 63;
  const int quad = lane >> 4, l16 = lane & 15;
  const int r8 = lane >> 3, c8 = lane & 7;
  const int b = bh >> 4, h = bh & 15;

  const u16* Qh = Q  + (size_t)bh * SEQ * DK;
  const u16* Kh = Kx + (size_t)bh * SEQ * DK;
  const u16* Vh = Vt + (size_t)bh * DK * SEQ;

  short8 vone;
#pragma unroll
  for (int j = 0; j < 8; ++j) vone[j] = (l16 == 0) ? (short)0x3F80 : (short)0;

  for (int half = 0; half < 2; ++half) {
    const int qtb = half == 0 ? (15 - (int)blockIdx.y) : (int)blockIdx.y;
    const int q0  = qtb * 128;

    short8 qf[2][2];
#pragma unroll
    for (int qp = 0; qp < 2; ++qp) {
      const int qrow = q0 + w * 32 + qp * 16 + l16;
#pragma unroll
      for (int hh = 0; hh < 2; ++hh)
        qf[qp][hh] = *(const short8*)(Qh + (size_t)qrow * DK + hh * 32 + quad * 8);
    }

    floatx4 o[2][4], ls[2];
#pragma unroll
    for (int qp = 0; qp < 2; ++qp) {
      ls[qp] = floatx4{0.f, 0.f, 0.f, 0.f};
#pragma unroll
      for (int dt = 0; dt < 4; ++dt) o[qp][dt] = floatx4{0.f, 0.f, 0.f, 0.f};
    }

    const int ktmax = 2 * qtb + 2;
    for (int kt = 0; kt < ktmax; ++kt) {
      const int k0 = kt * 64;
      __syncthreads();
#pragma unroll
      for (int c = 0; c < 2; ++c) {
        const int row8 = w * 16 + c * 8;   // wave-uniform
        const int sw   = (c8 ^ r8) * 8;
        async_copy16(Kh + (size_t)(k0 + row8 + r8) * DK + sw, Ks + row8 * 64);
        async_copy16(Vh + (size_t)(row8 + r8) * SEQ + k0 + sw, Vs + row8 * 64);
      }
      __syncthreads();

      short8 kf[4][2], vf[4][2];
#pragma unroll
      for (int nt = 0; nt < 4; ++nt)
#pragma unroll
        for (int hh = 0; hh < 2; ++hh) {
          kf[nt][hh] = *(const short8*)(Ks + (nt * 16 + l16) * 64 + (((hh * 4 + quad) ^ (l16 & 7)) * 8));
          vf[nt][hh] = *(const short8*)(Vs + (nt * 16 + l16) * 64 + (((hh * 4 + quad) ^ (l16 & 7)) * 8));
        }

#pragma unroll
      for (int qp = 0; qp < 2; ++qp) {
        const int frag0 = q0 + w * 32 + qp * 16;
        if (k0 <= frag0 + 15) {
          floatx4 sc[4];
#pragma unroll
          for (int nt = 0; nt < 4; ++nt) {
            floatx4 z = floatx4{0.f, 0.f, 0.f, 0.f};
            z = __builtin_amdgcn_mfma_f32_16x16x32_bf16(qf[qp][0], kf[nt][0], z, 0, 0, 0);
            z = __builtin_amdgcn_mfma_f32_16x16x32_bf16(qf[qp][1], kf[nt][1], z, 0, 0, 0);
            sc[nt] = z;
          }
          const bool diag = (k0 + 63 > frag0);
#pragma unroll
          for (int nt = 0; nt < 4; ++nt)
#pragma unroll
            for (int r = 0; r < 4; ++r) {
              float s = sc[nt][r];          // Q pre-scaled: already log2 domain
              if (diag) {
                const int col = k0 + nt * 16 + l16;
                const int row = frag0 + quad * 4 + r;
                if (col > row) s = -1e30f;
              }
              sc[nt][r] = __builtin_amdgcn_exp2f(s);
            }
          short* Pp = Ps + (w * 32 + qp * 16) * AT_STR;
#pragma unroll
          for (int nt = 0; nt < 4; ++nt)
#pragma unroll
            for (int r = 0; r < 4; ++r)
              Pp[(quad * 4 + r) * AT_STR + nt * 16 + l16] = (short)f2bf_fast(sc[nt][r]);
          short8 pf[2];
#pragma unroll
          for (int hh = 0; hh < 2; ++hh)
            pf[hh] = *(const short8*)(Pp + l16 * AT_STR + hh * 32 + quad * 8);
#pragma unroll
          for (int dt = 0; dt < 4; ++dt) {
            o[qp][dt] = __builtin_amdgcn_mfma_f32_16x16x32_bf16(pf[0], vf[dt][0], o[qp][dt], 0, 0, 0);
            o[qp][dt] = __builtin_amdgcn_mfma_f32_16x16x32_bf16(pf[1], vf[dt][1], o[qp][dt], 0, 0, 0);
          }
          ls[qp] = __builtin_amdgcn_mfma_f32_16x16x32_bf16(pf[0], vone, ls[qp], 0, 0, 0);
          ls[qp] = __builtin_amdgcn_mfma_f32_16x16x32_bf16(pf[1], vone, ls[qp], 0, 0, 0);
        }
      }
    }

    // epilogue for this q-tile: O'[b, s, h*64+d] bf16
#pragma unroll
    for (int qp = 0; qp < 2; ++qp) {
      const int frag0 = q0 + w * 32 + qp * 16;
#pragma unroll
      for (int r = 0; r < 4; ++r) {
        const float lv  = __shfl(ls[qp][r], lane & 48);
        const float inv = 1.0f / fmaxf(lv, 1e-20f);
        const int row   = frag0 + quad * 4 + r;
        const size_t base = ((size_t)b * SEQ + row) * DM + h * DK;
#pragma unroll
        for (int dt = 0; dt < 4; ++dt)
          O[base + dt * 16 + l16] = f2bf(o[qp][dt][r] * inv);
      }
    }
  }
}

// ---------------------------------------------------------------------------
// Output projection: out = O'(bf16) @ Wo_b^T + bo, fp32 out. grid = (64, 8).
// ---------------------------------------------------------------------------
__global__ __launch_bounds__(256, 2)
void oproj_kernel(const u16* __restrict__ A, const u16* __restrict__ Wob,
                  const float* __restrict__ bo, float* __restrict__ out)
{
  const int m0 = blockIdx.x * 128, n0 = blockIdx.y * 128;
  floatx4 acc[4][4];
  gemm_core_bb(A, Wob, m0, n0, acc);

  const int tid = threadIdx.x;
  const int w = tid >> 6, lane = tid & 63;
  const int wm = w >> 1, wn = w & 1, quad = lane >> 4, l16 = lane & 15;

#pragma unroll
  for (int nt = 0; nt < 4; ++nt) {
    const int n = n0 + wn * 64 + nt * 16 + l16;
    const float bb = bo[n];
#pragma unroll
    for (int mt = 0; mt < 4; ++mt)
#pragma unroll
      for (int r = 0; r < 4; ++r) {
        const int m = m0 + wm * 64 + mt * 16 + quad * 4 + r;
        out[(size_t)m * DM + n] = acc[mt][nt][r] + bb;
      }
  }
}

extern "C" void kernel_launch(void* const* d_in, const int* in_sizes, int n_in,
                              void* d_out, int out_size, void* d_ws, size_t ws_size,
                              hipStream_t stream)
{
  const float* x  = (const float*)d_in[0];
  const float* Wq = (const float*)d_in[1];
  const float* bq = (const float*)d_in[2];
  const float* Wk = (const float*)d_in[3];
  const float* bk = (const float*)d_in[4];
  const float* Wv = (const float*)d_in[5];
  const float* bv = (const float*)d_in[6];
  const float* Wo = (const float*)d_in[7];
  const float* bo = (const float*)d_in[8];
  float* out = (float*)d_out;

  // ws (64 MiB): Q, K, Vt, O'  (qws doubles as Wo_b after attn)
  u16* qws  = (u16*)d_ws;                       // (b,h,s,d)  bf16, 16 MiB
  u16* kws  = qws  + (size_t)M_ROWS * DM;       // (b,h,s,d)  bf16, 16 MiB
  u16* vtws = kws  + (size_t)M_ROWS * DM;       // (b,h,d,s)  bf16, 16 MiB
  u16* ows  = vtws + (size_t)M_ROWS * DM;       // O' (b,s,h*d) bf16, 16 MiB

  // d_out doubles as scratch until oproj overwrites all of it:
  u16* xb = (u16*)d_out;
  u16* wb = xb + (size_t)M_ROWS * DM;
  u16* wo_b = qws;                              // qws dead after attn

  cvt4_kernel<<<dim3(1024, 4), 256, 0, stream>>>(x, Wq, Wk, Wv, xb, wb);
  qkv_kernel <<<dim3(64, 24), 256, 0, stream>>>(xb, wb, bq, bk, bv, qws, kws, vtws);
  attn_kernel<<<dim3(64, 8), 256, 0, stream>>>(qws, kws, vtws, ows);
  cvt1_kernel<<<dim3(1024), 256, 0, stream>>>(Wo, wo_b, (DM * DM) / 4);
  oproj_kernel<<<dim3(64, 8), 256, 0, stream>>>(ows, wo_b, bo, out);
}